// Round 1
// baseline (5009.981 us; speedup 1.0000x reference)
//
#include <hip/hip_runtime.h>
#include <hip/hip_cooperative_groups.h>

// Problem constants
#define SEQ   512
#define BATCH 64
#define IS    512
#define HS    512
#define G4    2048   // 4*HS

typedef _Float16 half8 __attribute__((ext_vector_type(8)));
typedef _Float16 half4 __attribute__((ext_vector_type(4)));
typedef float floatx4 __attribute__((ext_vector_type(4)));

__device__ __forceinline__ float sigm(float x) {
    return 1.0f / (1.0f + __expf(-x));
}
__device__ __forceinline__ float tanh_(float x) {
    float e = __expf(-2.0f * fabsf(x));
    float r = (1.0f - e) / (1.0f + e);
    return copysignf(r, x);
}

// ---------------------------------------------------------------------------
// 1) fp32 -> f16 convert (x), vectorized 4-wide
// ---------------------------------------------------------------------------
__global__ void convert_f32_f16(const float* __restrict__ in,
                                _Float16* __restrict__ out, int n4) {
    int i = blockIdx.x * blockDim.x + threadIdx.x;
    if (i < n4) {
        float4 v = ((const float4*)in)[i];
        half4 o = { (_Float16)v.x, (_Float16)v.y, (_Float16)v.z, (_Float16)v.w };
        ((half4*)out)[i] = o;
    }
}

// ---------------------------------------------------------------------------
// 2) W [512][2048] fp32  ->  Wt [2048][512] f16  (k-contiguous for MFMA frags)
// ---------------------------------------------------------------------------
__global__ void transpose_w(const float* __restrict__ in, _Float16* __restrict__ out) {
    __shared__ _Float16 tile[64][72];   // +8 pad
    int bk = blockIdx.x & 7;            // k tile  (512/64)
    int bn = blockIdx.x >> 3;           // n tile  (2048/64)
    int c = threadIdx.x & 63;
    int r4 = threadIdx.x >> 6;          // 0..3
    #pragma unroll
    for (int rr = 0; rr < 16; rr++) {
        int k = rr * 4 + r4;
        tile[k][c] = (_Float16)in[(size_t)(bk * 64 + k) * 2048 + bn * 64 + c];
    }
    __syncthreads();
    #pragma unroll
    for (int rr = 0; rr < 16; rr++) {
        int n = rr * 4 + r4;
        out[(size_t)(bn * 64 + n) * 512 + bk * 64 + c] = tile[c][n];
    }
}

// ---------------------------------------------------------------------------
// 3) x_proj GEMM: C[32768 x 2048] = A[32768 x 512] * B[512 x 2048]
//    A = x (f16, row-major [b*512+s][k]),  Bt = Wt_ih (f16 [n][k])
//    Output written as x_proj[t][b][col] (f16).
//    128x128 tile, BK=32, 4 waves, each wave 64x64 via 4x4 16x16x32 MFMAs.
// ---------------------------------------------------------------------------
__global__ void __launch_bounds__(256, 2) gemm_xproj(
    const _Float16* __restrict__ A,
    const _Float16* __restrict__ Bt,
    _Float16* __restrict__ xp) {
    __shared__ _Float16 As[4096];   // 128 rows x 32 k
    __shared__ _Float16 Bs[4096];   // 128 n-rows x 32 k
    const int tid = threadIdx.x;
    const int w = tid >> 6, l = tid & 63, lr = l & 15, q = l >> 4;
    const int bm = blockIdx.x & 255, bn = blockIdx.x >> 8;
    const int row0 = bm * 128, col0 = bn * 128;
    const int wr = (w >> 1) * 64, wc = (w & 1) * 64;

    floatx4 zz = {0.f, 0.f, 0.f, 0.f};
    floatx4 acc[4][4];
    #pragma unroll
    for (int mt = 0; mt < 4; mt++)
        #pragma unroll
        for (int ct = 0; ct < 4; ct++) acc[mt][ct] = zz;

    for (int kt = 0; kt < 16; kt++) {
        __syncthreads();
        #pragma unroll
        for (int rnd = 0; rnd < 2; rnd++) {
            int o = tid * 16 + rnd * 4096;     // byte offset into tile
            int r = o >> 6;                    // tile row (64 B rows)
            int ke = (o & 63) >> 1;            // k element offset
            *(half8*)((char*)As + o) = *(const half8*)(A  + (size_t)(row0 + r) * 512 + kt * 32 + ke);
            *(half8*)((char*)Bs + o) = *(const half8*)(Bt + (size_t)(col0 + r) * 512 + kt * 32 + ke);
        }
        __syncthreads();
        half8 af[4], bf[4];
        #pragma unroll
        for (int mt = 0; mt < 4; mt++)
            af[mt] = *(const half8*)(As + (wr + mt * 16 + lr) * 32 + q * 8);
        #pragma unroll
        for (int ct = 0; ct < 4; ct++)
            bf[ct] = *(const half8*)(Bs + (wc + ct * 16 + lr) * 32 + q * 8);
        #pragma unroll
        for (int mt = 0; mt < 4; mt++)
            #pragma unroll
            for (int ct = 0; ct < 4; ct++)
                acc[mt][ct] = __builtin_amdgcn_mfma_f32_16x16x32_f16(af[mt], bf[ct], acc[mt][ct], 0, 0, 0);
    }
    // epilogue: C row r -> (t = r & 511, b = r >> 9); store f16
    #pragma unroll
    for (int mt = 0; mt < 4; mt++) {
        #pragma unroll
        for (int r = 0; r < 4; r++) {
            int row = row0 + wr + mt * 16 + q * 4 + r;
            int t = row & 511, b = row >> 9;
            _Float16* dst = xp + ((size_t)(t * 64 + b)) * 2048 + col0 + wc;
            #pragma unroll
            for (int ct = 0; ct < 4; ct++)
                dst[ct * 16 + lr] = (_Float16)acc[mt][ct][r];
        }
    }
}

// ---------------------------------------------------------------------------
// 4) Recurrent scan. Cooperative: 32 WGs x 256 threads.
//    WG wg owns hidden units [wg*16, wg*16+16) -> 64 gate columns
//    (column-tile ct == gate index: 0=i 1=f 2=g 3=o).
//    W_hh slice (64 cols x 512 k, f16) LDS-resident, XOR-swizzled granules.
//    Wave w owns batch rows [w*16, w*16+16). c-state lives in VGPRs.
//    h broadcast through global double buffer + grid.sync per step.
// ---------------------------------------------------------------------------
__global__ void __launch_bounds__(256, 1) lstm_scan(
    const _Float16* __restrict__ xp,    // [512][64][2048] f16
    const _Float16* __restrict__ wt,    // Wt_hh [2048][512] f16
    _Float16* __restrict__ hb,          // 2 x [64][512] f16 double buffer
    const float* __restrict__ bias,     // [2048]
    const float* __restrict__ h0,       // [64][512]
    const float* __restrict__ c0,       // [64][512]
    float* __restrict__ out) {          // hidden_seq | h_T | c_T
    __shared__ _Float16 wlds[32768];    // 64 cols x 512 k = 64 KB
    const int wg = blockIdx.x;          // 0..31
    const int tid = threadIdx.x;
    const int w = tid >> 6;             // wave 0..3
    const int l = tid & 63;
    const int lr = l & 15;
    const int q = l >> 4;
    const int myhid = wg * 16 + lr;

    // Stage W slice into LDS. Column n = gate*16 + u maps to Wt row gate*512 + wg*16 + u.
    // Granule swizzle: 16B granule g stored at position g ^ (n & 7)  -> conflict-free frag reads.
    for (int idx = tid; idx < 4096; idx += 256) {
        int n = idx >> 6, g = idx & 63;
        int gate = n >> 4, u = n & 15;
        half8 v = *(const half8*)(wt + (size_t)(gate * 512 + wg * 16 + u) * 512 + g * 8);
        *(half8*)(wlds + n * 512 + ((g ^ (n & 7)) * 8)) = v;
    }
    // Init h double-buffer slot 0 from h0 (each WG a disjoint 1024-elem slice)
    for (int i = wg * 256 + tid; i < 32768; i += 8192)
        hb[i] = (_Float16)h0[i];

    float bs[4], c[4];
    #pragma unroll
    for (int g4 = 0; g4 < 4; g4++) bs[g4] = bias[g4 * 512 + myhid];
    #pragma unroll
    for (int r = 0; r < 4; r++) c[r] = c0[(w * 16 + q * 4 + r) * 512 + myhid];

    cooperative_groups::grid_group grid = cooperative_groups::this_grid();
    __syncthreads();
    grid.sync();

    for (int t = 0; t < 512; t++) {
        const _Float16* hprev = hb + (t & 1) * 32768;
        _Float16* hnext = hb + ((t + 1) & 1) * 32768;

        // Prefetch x_proj contributions (C-layout aligned: row = q*4+r, col = lr)
        float xpv[4][4];
        #pragma unroll
        for (int r = 0; r < 4; r++) {
            const _Float16* base = xp + ((size_t)(t * 64 + w * 16 + q * 4 + r)) * 2048 + myhid;
            #pragma unroll
            for (int g4 = 0; g4 < 4; g4++) xpv[g4][r] = (float)base[g4 * 512];
        }

        // A-fragments straight from global h buffer (L2/L3 hot): m = lr
        half8 a[16];
        #pragma unroll
        for (int kt = 0; kt < 16; kt++)
            a[kt] = *(const half8*)(hprev + (w * 16 + lr) * 512 + kt * 32 + q * 8);

        floatx4 zz = {0.f, 0.f, 0.f, 0.f};
        floatx4 acc[4] = {zz, zz, zz, zz};
        #pragma unroll
        for (int kt = 0; kt < 16; kt++) {
            #pragma unroll
            for (int g4 = 0; g4 < 4; g4++) {
                int n = g4 * 16 + lr;
                half8 b8 = *(const half8*)(wlds + n * 512 + (((kt * 4 + q) ^ (n & 7)) * 8));
                acc[g4] = __builtin_amdgcn_mfma_f32_16x16x32_f16(a[kt], b8, acc[g4], 0, 0, 0);
            }
        }

        // Cell update in registers; acc[gate][r] for (batch = w*16+q*4+r, hid = myhid)
        #pragma unroll
        for (int r = 0; r < 4; r++) {
            int b = w * 16 + q * 4 + r;
            float gi = acc[0][r] + xpv[0][r] + bs[0];
            float gf = acc[1][r] + xpv[1][r] + bs[1];
            float gg = acc[2][r] + xpv[2][r] + bs[2];
            float go = acc[3][r] + xpv[3][r] + bs[3];
            float i_ = sigm(gi), f_ = sigm(gf), gv = tanh_(gg), o_ = sigm(go);
            c[r] = f_ * c[r] + i_ * gv;
            float h = o_ * tanh_(c[r]);
            hnext[b * 512 + myhid] = (_Float16)h;
            out[(size_t)b * 262144 + (size_t)t * 512 + myhid] = h;
            if (t == 511) {
                out[16777216 + b * 512 + myhid] = h;        // h_T
                out[16777216 + 32768 + b * 512 + myhid] = c[r];  // c_T
            }
        }
        grid.sync();
    }
}

// ---------------------------------------------------------------------------
// launch
// ---------------------------------------------------------------------------
extern "C" void kernel_launch(void* const* d_in, const int* in_sizes, int n_in,
                              void* d_out, int out_size, void* d_ws, size_t ws_size,
                              hipStream_t stream) {
    const float* x    = (const float*)d_in[0];
    const float* wih  = (const float*)d_in[1];
    const float* whh  = (const float*)d_in[2];
    const float* bias = (const float*)d_in[3];
    const float* h0   = (const float*)d_in[4];
    const float* c0   = (const float*)d_in[5];
    float* out = (float*)d_out;

    char* ws = (char*)d_ws;
    _Float16* x16  = (_Float16*)(ws);                 // 32 MB
    _Float16* wtih = (_Float16*)(ws + 33554432);      // 2 MB
    _Float16* wthh = (_Float16*)(ws + 35651584);      // 2 MB
    _Float16* xp   = (_Float16*)(ws + 37748736);      // 128 MB
    _Float16* hb   = (_Float16*)(ws + 171966464);     // 128 KB (double buffer)

    // x fp32 -> f16
    convert_f32_f16<<<16384, 256, 0, stream>>>(x, x16, BATCH * SEQ * IS / 4);
    // weight transposes (fp32 [512][2048] -> f16 [2048][512])
    transpose_w<<<256, 256, 0, stream>>>(wih, wtih);
    transpose_w<<<256, 256, 0, stream>>>(whh, wthh);
    // input projection
    gemm_xproj<<<4096, 256, 0, stream>>>(x16, wtih, xp);
    // recurrent scan (cooperative)
    void* args[] = {(void*)&xp, (void*)&wthh, (void*)&hb, (void*)&bias,
                    (void*)&h0, (void*)&c0, (void*)&out};
    hipLaunchCooperativeKernel((void*)lstm_scan, dim3(32), dim3(256), args, 0, stream);
}

// Round 2
// 3242.530 us; speedup vs baseline: 1.5451x; 1.5451x over previous
//
#include <hip/hip_runtime.h>
#include <hip/hip_cooperative_groups.h>

// Problem constants
#define SEQ   512
#define BATCH 64
#define IS    512
#define HS    512
#define G4    2048   // 4*HS

typedef _Float16 half8 __attribute__((ext_vector_type(8)));
typedef _Float16 half4 __attribute__((ext_vector_type(4)));
typedef float floatx4 __attribute__((ext_vector_type(4)));
typedef unsigned long long ull;

__device__ __forceinline__ float sigm(float x) {
    return 1.0f / (1.0f + __expf(-x));
}
__device__ __forceinline__ float tanh_(float x) {
    float e = __expf(-2.0f * fabsf(x));
    float r = (1.0f - e) / (1.0f + e);
    return copysignf(r, x);
}

// ---------------------------------------------------------------------------
// 1) fp32 -> f16 convert (x), vectorized 4-wide
// ---------------------------------------------------------------------------
__global__ void convert_f32_f16(const float* __restrict__ in,
                                _Float16* __restrict__ out, int n4) {
    int i = blockIdx.x * blockDim.x + threadIdx.x;
    if (i < n4) {
        float4 v = ((const float4*)in)[i];
        half4 o = { (_Float16)v.x, (_Float16)v.y, (_Float16)v.z, (_Float16)v.w };
        ((half4*)out)[i] = o;
    }
}

// ---------------------------------------------------------------------------
// 2) W [512][2048] fp32  ->  Wt [2048][512] f16  (k-contiguous for MFMA frags)
// ---------------------------------------------------------------------------
__global__ void transpose_w(const float* __restrict__ in, _Float16* __restrict__ out) {
    __shared__ _Float16 tile[64][72];   // +8 pad
    int bk = blockIdx.x & 7;            // k tile  (512/64)
    int bn = blockIdx.x >> 3;           // n tile  (2048/64)
    int c = threadIdx.x & 63;
    int r4 = threadIdx.x >> 6;          // 0..3
    #pragma unroll
    for (int rr = 0; rr < 16; rr++) {
        int k = rr * 4 + r4;
        tile[k][c] = (_Float16)in[(size_t)(bk * 64 + k) * 2048 + bn * 64 + c];
    }
    __syncthreads();
    #pragma unroll
    for (int rr = 0; rr < 16; rr++) {
        int n = rr * 4 + r4;
        out[(size_t)(bn * 64 + n) * 512 + bk * 64 + c] = tile[c][n];
    }
}

// ---------------------------------------------------------------------------
// 3) x_proj GEMM: C[32768 x 2048] = A[32768 x 512] * B[512 x 2048]
// ---------------------------------------------------------------------------
__global__ void __launch_bounds__(256, 2) gemm_xproj(
    const _Float16* __restrict__ A,
    const _Float16* __restrict__ Bt,
    _Float16* __restrict__ xp) {
    __shared__ _Float16 As[4096];   // 128 rows x 32 k
    __shared__ _Float16 Bs[4096];   // 128 n-rows x 32 k
    const int tid = threadIdx.x;
    const int w = tid >> 6, l = tid & 63, lr = l & 15, q = l >> 4;
    const int bm = blockIdx.x & 255, bn = blockIdx.x >> 8;
    const int row0 = bm * 128, col0 = bn * 128;
    const int wr = (w >> 1) * 64, wc = (w & 1) * 64;

    floatx4 zz = {0.f, 0.f, 0.f, 0.f};
    floatx4 acc[4][4];
    #pragma unroll
    for (int mt = 0; mt < 4; mt++)
        #pragma unroll
        for (int ct = 0; ct < 4; ct++) acc[mt][ct] = zz;

    for (int kt = 0; kt < 16; kt++) {
        __syncthreads();
        #pragma unroll
        for (int rnd = 0; rnd < 2; rnd++) {
            int o = tid * 16 + rnd * 4096;     // byte offset into tile
            int r = o >> 6;                    // tile row (64 B rows)
            int ke = (o & 63) >> 1;            // k element offset
            *(half8*)((char*)As + o) = *(const half8*)(A  + (size_t)(row0 + r) * 512 + kt * 32 + ke);
            *(half8*)((char*)Bs + o) = *(const half8*)(Bt + (size_t)(col0 + r) * 512 + kt * 32 + ke);
        }
        __syncthreads();
        half8 af[4], bf[4];
        #pragma unroll
        for (int mt = 0; mt < 4; mt++)
            af[mt] = *(const half8*)(As + (wr + mt * 16 + lr) * 32 + q * 8);
        #pragma unroll
        for (int ct = 0; ct < 4; ct++)
            bf[ct] = *(const half8*)(Bs + (wc + ct * 16 + lr) * 32 + q * 8);
        #pragma unroll
        for (int mt = 0; mt < 4; mt++)
            #pragma unroll
            for (int ct = 0; ct < 4; ct++)
                acc[mt][ct] = __builtin_amdgcn_mfma_f32_16x16x32_f16(af[mt], bf[ct], acc[mt][ct], 0, 0, 0);
    }
    // epilogue: C row r -> (t = r & 511, b = r >> 9); store f16
    #pragma unroll
    for (int mt = 0; mt < 4; mt++) {
        #pragma unroll
        for (int r = 0; r < 4; r++) {
            int row = row0 + wr + mt * 16 + q * 4 + r;
            int t = row & 511, b = row >> 9;
            _Float16* dst = xp + ((size_t)(t * 64 + b)) * 2048 + col0 + wc;
            #pragma unroll
            for (int ct = 0; ct < 4; ct++)
                dst[ct * 16 + lr] = (_Float16)acc[mt][ct][r];
        }
    }
}

// ---------------------------------------------------------------------------
// 4) Recurrent scan. 32 WGs x 256 threads, cooperative (co-residency only —
//    no grid.sync). Hand-rolled flag barrier; h exchange via agent-scope
//    relaxed atomics (sc0/sc1 → coherence point), NO cache-wide fences.
//    Flag protocol: flag[wg]=1 after h0 staged; step t waits all flags>=t+1,
//    stores h_{t+1} into slot (t+1)&1, drains, sets flag=t+2.
//    Double buffer + max-skew-1 => race-free.
// ---------------------------------------------------------------------------
__global__ void __launch_bounds__(256, 1) lstm_scan(
    const _Float16* __restrict__ xp,    // [512][64][2048] f16
    const _Float16* __restrict__ wt,    // Wt_hh [2048][512] f16
    _Float16* __restrict__ hb,          // 2 x [64][512] f16 double buffer
    const float* __restrict__ bias,     // [2048]
    const float* __restrict__ h0,       // [64][512]
    const float* __restrict__ c0,       // [64][512]
    float* __restrict__ out,            // hidden_seq | h_T | c_T
    int* __restrict__ flags) {          // 32 flags, padded 32 ints apart
    __shared__ _Float16 wlds[32768];    // 64 cols x 512 k = 64 KB
    const int wg = blockIdx.x;          // 0..31
    const int tid = threadIdx.x;
    const int w = tid >> 6;             // wave 0..3
    const int l = tid & 63;
    const int lr = l & 15;
    const int q = l >> 4;
    const int myhid = wg * 16 + lr;

    // Stage W slice into LDS (gate*16+u columns; XOR granule swizzle).
    for (int idx = tid; idx < 4096; idx += 256) {
        int n = idx >> 6, g = idx & 63;
        int gate = n >> 4, u = n & 15;
        half8 v = *(const half8*)(wt + (size_t)(gate * 512 + wg * 16 + u) * 512 + g * 8);
        *(half8*)(wlds + n * 512 + ((g ^ (n & 7)) * 8)) = v;
    }

    // Init h slot 0 from h0 with device-visible stores (disjoint slices per WG)
    unsigned short* hbu = (unsigned short*)hb;
    for (int i = wg * 256 + tid; i < 32768; i += 8192) {
        union { _Float16 f; unsigned short u; } cv;
        cv.f = (_Float16)h0[i];
        __hip_atomic_store(hbu + i, cv.u, __ATOMIC_RELAXED, __HIP_MEMORY_SCOPE_AGENT);
    }

    float bs[4], c[4];
    #pragma unroll
    for (int g4 = 0; g4 < 4; g4++) bs[g4] = bias[g4 * 512 + myhid];
    #pragma unroll
    for (int r = 0; r < 4; r++) c[r] = c0[(w * 16 + q * 4 + r) * 512 + myhid];

    asm volatile("s_waitcnt vmcnt(0)" ::: "memory");
    __syncthreads();
    if (tid == 0)
        __hip_atomic_store(&flags[wg * 32], 1, __ATOMIC_RELAXED, __HIP_MEMORY_SCOPE_AGENT);

    for (int t = 0; t < 512; t++) {
        // xp prefetch — independent of the barrier, issue before the spin
        float xpv[4][4];
        #pragma unroll
        for (int r = 0; r < 4; r++) {
            const _Float16* base = xp + ((size_t)(t * 64 + w * 16 + q * 4 + r)) * 2048 + myhid;
            #pragma unroll
            for (int g4 = 0; g4 < 4; g4++) xpv[g4][r] = (float)base[g4 * 512];
        }

        // Wait: all 32 WGs have published h_t (lane-parallel poll)
        if (tid < 32) {
            while (__hip_atomic_load(&flags[tid * 32], __ATOMIC_RELAXED,
                                     __HIP_MEMORY_SCOPE_AGENT) < t + 1)
                __builtin_amdgcn_s_sleep(1);
        }
        __syncthreads();

        // A-fragments from h slot t&1 (coherence-point loads, 8B each)
        ull* hsrc = (ull*)(hb + (t & 1) * 32768);
        const int abase = (w * 16 + lr) * 128;
        union HU { ull u[2]; half8 v; } a[16];
        #pragma unroll
        for (int kt = 0; kt < 16; kt++) {
            int idx = abase + kt * 8 + q * 2;
            a[kt].u[0] = __hip_atomic_load(hsrc + idx,     __ATOMIC_RELAXED, __HIP_MEMORY_SCOPE_AGENT);
            a[kt].u[1] = __hip_atomic_load(hsrc + idx + 1, __ATOMIC_RELAXED, __HIP_MEMORY_SCOPE_AGENT);
        }

        floatx4 zz = {0.f, 0.f, 0.f, 0.f};
        floatx4 acc[4] = {zz, zz, zz, zz};
        #pragma unroll
        for (int kt = 0; kt < 16; kt++) {
            #pragma unroll
            for (int g4 = 0; g4 < 4; g4++) {
                int n = g4 * 16 + lr;
                half8 b8 = *(const half8*)(wlds + n * 512 + (((kt * 4 + q) ^ (n & 7)) * 8));
                acc[g4] = __builtin_amdgcn_mfma_f32_16x16x32_f16(a[kt].v, b8, acc[g4], 0, 0, 0);
            }
        }

        // Cell update; publish h_{t+1} (device-visible)
        unsigned short* hdst = hbu + ((t + 1) & 1) * 32768;
        float hv[4];
        #pragma unroll
        for (int r = 0; r < 4; r++) {
            float gi = acc[0][r] + xpv[0][r] + bs[0];
            float gf = acc[1][r] + xpv[1][r] + bs[1];
            float gg = acc[2][r] + xpv[2][r] + bs[2];
            float go = acc[3][r] + xpv[3][r] + bs[3];
            float i_ = sigm(gi), f_ = sigm(gf), gv = tanh_(gg), o_ = sigm(go);
            c[r] = f_ * c[r] + i_ * gv;
            float h = o_ * tanh_(c[r]);
            hv[r] = h;
            int b = w * 16 + q * 4 + r;
            union { _Float16 f; unsigned short u; } cv;
            cv.f = (_Float16)h;
            __hip_atomic_store(hdst + b * 512 + myhid, cv.u, __ATOMIC_RELAXED, __HIP_MEMORY_SCOPE_AGENT);
        }

        // Drain h stores (per-wave), then publish flag
        asm volatile("s_waitcnt vmcnt(0)" ::: "memory");
        __syncthreads();
        if (tid == 0)
            __hip_atomic_store(&flags[wg * 32], t + 2, __ATOMIC_RELAXED, __HIP_MEMORY_SCOPE_AGENT);

        // Off-critical-path output stores (normal, cached)
        #pragma unroll
        for (int r = 0; r < 4; r++) {
            int b = w * 16 + q * 4 + r;
            out[(size_t)b * 262144 + (size_t)t * 512 + myhid] = hv[r];
            if (t == 511) {
                out[16777216 + b * 512 + myhid] = hv[r];            // h_T
                out[16777216 + 32768 + b * 512 + myhid] = c[r];     // c_T
            }
        }
    }
}

// ---------------------------------------------------------------------------
// launch
// ---------------------------------------------------------------------------
extern "C" void kernel_launch(void* const* d_in, const int* in_sizes, int n_in,
                              void* d_out, int out_size, void* d_ws, size_t ws_size,
                              hipStream_t stream) {
    const float* x    = (const float*)d_in[0];
    const float* wih  = (const float*)d_in[1];
    const float* whh  = (const float*)d_in[2];
    const float* bias = (const float*)d_in[3];
    const float* h0   = (const float*)d_in[4];
    const float* c0   = (const float*)d_in[5];
    float* out = (float*)d_out;

    char* ws = (char*)d_ws;
    _Float16* x16  = (_Float16*)(ws);                 // 32 MB
    _Float16* wtih = (_Float16*)(ws + 33554432);      // 2 MB
    _Float16* wthh = (_Float16*)(ws + 35651584);      // 2 MB
    _Float16* xp   = (_Float16*)(ws + 37748736);      // 128 MB
    _Float16* hb   = (_Float16*)(ws + 171966464);     // 128 KB (double buffer)
    int*      flags = (int*)(ws + 172097536);         // 4 KB barrier flags

    hipMemsetAsync(flags, 0, 4096, stream);
    // x fp32 -> f16
    convert_f32_f16<<<16384, 256, 0, stream>>>(x, x16, BATCH * SEQ * IS / 4);
    // weight transposes (fp32 [512][2048] -> f16 [2048][512])
    transpose_w<<<256, 256, 0, stream>>>(wih, wtih);
    transpose_w<<<256, 256, 0, stream>>>(whh, wthh);
    // input projection
    gemm_xproj<<<4096, 256, 0, stream>>>(x16, wtih, xp);
    // recurrent scan (cooperative launch for co-residency; custom barrier inside)
    void* args[] = {(void*)&xp, (void*)&wthh, (void*)&hb, (void*)&bias,
                    (void*)&h0, (void*)&c0, (void*)&out, (void*)&flags};
    hipLaunchCooperativeKernel((void*)lstm_scan, dim3(32), dim3(256), args, 0, stream);
}

// Round 5
// 2291.148 us; speedup vs baseline: 2.1867x; 1.4152x over previous
//
#include <hip/hip_runtime.h>

// Problem constants
#define SEQ   512
#define BATCH 64
#define IS    512
#define HS    512
#define G4    2048   // 4*HS

typedef _Float16 half8 __attribute__((ext_vector_type(8)));
typedef _Float16 half4 __attribute__((ext_vector_type(4)));
typedef float floatx4 __attribute__((ext_vector_type(4)));
typedef unsigned long long ull;

__device__ __forceinline__ float sigm(float x) {
    return 1.0f / (1.0f + __expf(-x));
}
__device__ __forceinline__ float tanh_(float x) {
    float e = __expf(-2.0f * fabsf(x));
    float r = (1.0f - e) / (1.0f + e);
    return copysignf(r, x);
}

// ---------------------------------------------------------------------------
// 1) fp32 -> f16 convert (x), vectorized 4-wide
// ---------------------------------------------------------------------------
__global__ void convert_f32_f16(const float* __restrict__ in,
                                _Float16* __restrict__ out, int n4) {
    int i = blockIdx.x * blockDim.x + threadIdx.x;
    if (i < n4) {
        float4 v = ((const float4*)in)[i];
        half4 o = { (_Float16)v.x, (_Float16)v.y, (_Float16)v.z, (_Float16)v.w };
        ((half4*)out)[i] = o;
    }
}

// ---------------------------------------------------------------------------
// 2) W [512][2048] fp32  ->  Wt [2048][512] f16  (k-contiguous for MFMA frags)
// ---------------------------------------------------------------------------
__global__ void transpose_w(const float* __restrict__ in, _Float16* __restrict__ out) {
    __shared__ _Float16 tile[64][72];   // +8 pad
    int bk = blockIdx.x & 7;            // k tile  (512/64)
    int bn = blockIdx.x >> 3;           // n tile  (2048/64)
    int c = threadIdx.x & 63;
    int r4 = threadIdx.x >> 6;          // 0..3
    #pragma unroll
    for (int rr = 0; rr < 16; rr++) {
        int k = rr * 4 + r4;
        tile[k][c] = (_Float16)in[(size_t)(bk * 64 + k) * 2048 + bn * 64 + c];
    }
    __syncthreads();
    #pragma unroll
    for (int rr = 0; rr < 16; rr++) {
        int n = rr * 4 + r4;
        out[(size_t)(bn * 64 + n) * 512 + bk * 64 + c] = tile[c][n];
    }
}

// ---------------------------------------------------------------------------
// 3) x_proj GEMM. Output layout (f16):  xp[t][wg][b][u][gate]
//    elem = ((t*32 + wg)*64 + b)*64 + u*4 + gate,  hid = wg*16+u
//    -> scan reads one half4 (4 gates) per (b,u), fully coalesced.
// ---------------------------------------------------------------------------
__global__ void __launch_bounds__(256, 2) gemm_xproj(
    const _Float16* __restrict__ A,
    const _Float16* __restrict__ Bt,
    _Float16* __restrict__ xp) {
    __shared__ _Float16 As[4096];   // 128 rows x 32 k
    __shared__ _Float16 Bs[4096];   // 128 n-rows x 32 k
    const int tid = threadIdx.x;
    const int w = tid >> 6, l = tid & 63, lr = l & 15, q = l >> 4;
    const int bm = blockIdx.x & 255, bn = blockIdx.x >> 8;
    const int row0 = bm * 128, col0 = bn * 128;
    const int wr = (w >> 1) * 64, wc = (w & 1) * 64;

    floatx4 zz = {0.f, 0.f, 0.f, 0.f};
    floatx4 acc[4][4];
    #pragma unroll
    for (int mt = 0; mt < 4; mt++)
        #pragma unroll
        for (int ct = 0; ct < 4; ct++) acc[mt][ct] = zz;

    for (int kt = 0; kt < 16; kt++) {
        __syncthreads();
        #pragma unroll
        for (int rnd = 0; rnd < 2; rnd++) {
            int o = tid * 16 + rnd * 4096;     // byte offset into tile
            int r = o >> 6;                    // tile row (64 B rows)
            int ke = (o & 63) >> 1;            // k element offset
            *(half8*)((char*)As + o) = *(const half8*)(A  + (size_t)(row0 + r) * 512 + kt * 32 + ke);
            *(half8*)((char*)Bs + o) = *(const half8*)(Bt + (size_t)(col0 + r) * 512 + kt * 32 + ke);
        }
        __syncthreads();
        half8 af[4], bf[4];
        #pragma unroll
        for (int mt = 0; mt < 4; mt++)
            af[mt] = *(const half8*)(As + (wr + mt * 16 + lr) * 32 + q * 8);
        #pragma unroll
        for (int ct = 0; ct < 4; ct++)
            bf[ct] = *(const half8*)(Bs + (wc + ct * 16 + lr) * 32 + q * 8);
        #pragma unroll
        for (int mt = 0; mt < 4; mt++)
            #pragma unroll
            for (int ct = 0; ct < 4; ct++)
                acc[mt][ct] = __builtin_amdgcn_mfma_f32_16x16x32_f16(af[mt], bf[ct], acc[mt][ct], 0, 0, 0);
    }
    // epilogue: C row -> (t = row & 511, b = row >> 9); scatter into new layout
    #pragma unroll
    for (int mt = 0; mt < 4; mt++) {
        #pragma unroll
        for (int r = 0; r < 4; r++) {
            int row = row0 + wr + mt * 16 + q * 4 + r;
            int t = row & 511, b = row >> 9;
            #pragma unroll
            for (int ct = 0; ct < 4; ct++) {
                int col = col0 + wc + ct * 16 + lr;
                int hid = col & 511, gate = col >> 9;
                int wgd = hid >> 4, u = hid & 15;
                xp[(size_t)(((t * 32 + wgd) * 64 + b)) * 64 + u * 4 + gate] =
                    (_Float16)acc[mt][ct][r];
            }
        }
    }
}

// ---------------------------------------------------------------------------
// 4) Recurrent scan. 32 WGs x 256 threads, REGULAR launch (32 blocks on 256
//    CUs are trivially co-resident; R3/R4 lesson: hipLaunchCooperativeKernel
//    silently failed validation for this kernel at >88 VGPRs — harness can't
//    surface the error, output stayed zero).
//    Hand-rolled flag barrier; coalesced h exchange:
//      hpub slot layout: [wg][b][u]  (wg 0..31, b 0..63, u 0..15) f16
//      publish: per-wave LDS transpose -> ONE 8B agent store per lane
//      read:    2x8B agent loads per frag, fully coalesced across the wave
//    W_hh slice split: gates i,f (g4=0,1) in LDS (32 KB, XOR-swizzled);
//    gates g,o (g4=2,3) in VGPRs (wreg[16][2] = 128 VGPRs).
// ---------------------------------------------------------------------------
__global__ void __launch_bounds__(256, 1) lstm_scan(
    const _Float16* __restrict__ xp,    // [t][wg][b][u][gate] f16
    const _Float16* __restrict__ wt,    // Wt_hh [2048][512] f16
    _Float16* __restrict__ hb,          // 2 x 32768 f16 (hpub double buffer)
    const float* __restrict__ bias,     // [2048]
    const float* __restrict__ h0,       // [64][512]
    const float* __restrict__ c0,       // [64][512]
    float* __restrict__ out,            // hidden_seq | h_T | c_T
    int* __restrict__ flags) {          // 32 flags, 128 B apart
    __shared__ _Float16 wlds[16384];    // 32 cols (gates i,f) x 512 k = 32 KB
    __shared__ _Float16 scr[4 * 320];   // per-wave 16x16 transpose scratch, row stride 20
    const int wg = blockIdx.x;          // 0..31
    const int tid = threadIdx.x;
    const int w = tid >> 6;             // wave 0..3
    const int l = tid & 63;
    const int lr = l & 15;
    const int q = l >> 4;
    const int myhid = wg * 16 + lr;
    _Float16* scrw = scr + w * 320;

    // Stage gates 0,1 (i,f) into LDS. Column n = gate*16+u <- Wt row gate*512+wg*16+u.
    // Granule swizzle: 16B granule g stored at g ^ (n & 7) -> conflict-free frag reads.
    for (int idx = tid; idx < 2048; idx += 256) {
        int n = idx >> 6, g = idx & 63;
        int gate = n >> 4, u = n & 15;
        half8 v = *(const half8*)(wt + (size_t)(gate * 512 + wg * 16 + u) * 512 + g * 8);
        *(half8*)(wlds + n * 512 + ((g ^ (n & 7)) * 8)) = v;
    }
    // Gates 2,3 (g,o) into registers: wreg[kt][gg] = B-frag (n = (2+gg)*16+lr, k = kt*32+q*8)
    half8 wreg[16][2];
    #pragma unroll
    for (int kt = 0; kt < 16; kt++)
        #pragma unroll
        for (int gg = 0; gg < 2; gg++)
            wreg[kt][gg] = *(const half8*)(wt + (size_t)((2 + gg) * 512 + wg * 16 + lr) * 512 + kt * 32 + q * 8);

    // Init h slot 0 in hpub layout from h0 (each WG its own 1024-elem slice)
    unsigned short* hbu = (unsigned short*)hb;
    for (int i = tid; i < 1024; i += 256) {
        int b = i >> 4, u = i & 15;
        union { _Float16 f; unsigned short us; } cv;
        cv.f = (_Float16)h0[b * 512 + wg * 16 + u];
        __hip_atomic_store(hbu + wg * 1024 + i, cv.us, __ATOMIC_RELAXED, __HIP_MEMORY_SCOPE_AGENT);
    }

    float bs[4], c[4];
    #pragma unroll
    for (int g4 = 0; g4 < 4; g4++) bs[g4] = bias[g4 * 512 + myhid];
    #pragma unroll
    for (int r = 0; r < 4; r++) c[r] = c0[(w * 16 + q * 4 + r) * 512 + myhid];

    asm volatile("s_waitcnt vmcnt(0)" ::: "memory");
    __syncthreads();
    if (tid == 0)
        __hip_atomic_store(&flags[wg * 32], 1, __ATOMIC_RELAXED, __HIP_MEMORY_SCOPE_AGENT);

    for (int t = 0; t < 512; t++) {
        // xp prefetch — coalesced half4 (4 gates) per (b,u); issue before spin
        float xpv[4][4];
        #pragma unroll
        for (int r = 0; r < 4; r++) {
            int b = w * 16 + q * 4 + r;
            half4 v = *(const half4*)(xp + (((size_t)t * 32 + wg) * 64 + b) * 64 + lr * 4);
            #pragma unroll
            for (int g4 = 0; g4 < 4; g4++) xpv[g4][r] = (float)v[g4];
        }

        // Wait: all 32 WGs have published h_t
        if (tid < 32) {
            while (__hip_atomic_load(&flags[tid * 32], __ATOMIC_RELAXED,
                                     __HIP_MEMORY_SCOPE_AGENT) < t + 1)
                __builtin_amdgcn_s_sleep(1);
        }
        __syncthreads();

        // A-fragments: m = lr (batch b0 = w*16+lr), k = kt*32 + q*8 + j
        // hpub elem = wg_src*1024 + b0*16 + u0 ; wg_src = 2kt + q/2, u0 = (q&1)*8
        const ull* hsrc = (const ull*)hb + (size_t)(t & 1) * 8192;
        const int b0 = w * 16 + lr;
        union HU { ull u[2]; half8 v; } a[16];
        #pragma unroll
        for (int kt = 0; kt < 16; kt++) {
            int idx = (2 * kt + (q >> 1)) * 256 + b0 * 4 + (q & 1) * 2;
            a[kt].u[0] = __hip_atomic_load(hsrc + idx,     __ATOMIC_RELAXED, __HIP_MEMORY_SCOPE_AGENT);
            a[kt].u[1] = __hip_atomic_load(hsrc + idx + 1, __ATOMIC_RELAXED, __HIP_MEMORY_SCOPE_AGENT);
        }

        floatx4 zz = {0.f, 0.f, 0.f, 0.f};
        floatx4 acc[4] = {zz, zz, zz, zz};
        #pragma unroll
        for (int kt = 0; kt < 16; kt++) {
            #pragma unroll
            for (int g4 = 0; g4 < 2; g4++) {
                int n = g4 * 16 + lr;
                half8 b8 = *(const half8*)(wlds + n * 512 + (((kt * 4 + q) ^ (n & 7)) * 8));
                acc[g4] = __builtin_amdgcn_mfma_f32_16x16x32_f16(a[kt].v, b8, acc[g4], 0, 0, 0);
            }
            #pragma unroll
            for (int gg = 0; gg < 2; gg++)
                acc[2 + gg] = __builtin_amdgcn_mfma_f32_16x16x32_f16(a[kt].v, wreg[kt][gg], acc[2 + gg], 0, 0, 0);
        }

        // Cell update; stage h tile into LDS for in-wave transpose
        float hv[4];
        #pragma unroll
        for (int r = 0; r < 4; r++) {
            float gi = acc[0][r] + xpv[0][r] + bs[0];
            float gf = acc[1][r] + xpv[1][r] + bs[1];
            float gg = acc[2][r] + xpv[2][r] + bs[2];
            float go = acc[3][r] + xpv[3][r] + bs[3];
            float i_ = sigm(gi), f_ = sigm(gf), gv = tanh_(gg), o_ = sigm(go);
            c[r] = f_ * c[r] + i_ * gv;
            float h = o_ * tanh_(c[r]);
            hv[r] = h;
            scrw[(q * 4 + r) * 20 + lr] = (_Float16)h;   // row = local b, col = u
        }
        asm volatile("s_waitcnt lgkmcnt(0)" ::: "memory");
        // lane l -> (local b = l>>2, u = (l&3)*4): one contiguous 8B chunk
        union { half4 h; ull u; } pk;
        pk.h = *(const half4*)(scrw + (l >> 2) * 20 + (l & 3) * 4);
        ull* hdst = (ull*)hb + (size_t)((t + 1) & 1) * 8192 + wg * 256 + w * 64 + l;
        __hip_atomic_store(hdst, pk.u, __ATOMIC_RELAXED, __HIP_MEMORY_SCOPE_AGENT);

        // Drain publish, then flag
        asm volatile("s_waitcnt vmcnt(0)" ::: "memory");
        __syncthreads();
        if (tid == 0)
            __hip_atomic_store(&flags[wg * 32], t + 2, __ATOMIC_RELAXED, __HIP_MEMORY_SCOPE_AGENT);

        // Off-critical-path output stores (normal, cached)
        #pragma unroll
        for (int r = 0; r < 4; r++) {
            int b = w * 16 + q * 4 + r;
            out[(size_t)b * 262144 + (size_t)t * 512 + myhid] = hv[r];
            if (t == 511) {
                out[16777216 + b * 512 + myhid] = hv[r];             // h_T
                out[16777216 + 32768 + b * 512 + myhid] = c[r];      // c_T
            }
        }
    }
}

// ---------------------------------------------------------------------------
// launch
// ---------------------------------------------------------------------------
extern "C" void kernel_launch(void* const* d_in, const int* in_sizes, int n_in,
                              void* d_out, int out_size, void* d_ws, size_t ws_size,
                              hipStream_t stream) {
    const float* x    = (const float*)d_in[0];
    const float* wih  = (const float*)d_in[1];
    const float* whh  = (const float*)d_in[2];
    const float* bias = (const float*)d_in[3];
    const float* h0   = (const float*)d_in[4];
    const float* c0   = (const float*)d_in[5];
    float* out = (float*)d_out;

    char* ws = (char*)d_ws;
    _Float16* x16  = (_Float16*)(ws);                 // 32 MB
    _Float16* wtih = (_Float16*)(ws + 33554432);      // 2 MB
    _Float16* wthh = (_Float16*)(ws + 35651584);      // 2 MB
    _Float16* xp   = (_Float16*)(ws + 37748736);      // 128 MB
    _Float16* hb   = (_Float16*)(ws + 171966464);     // 128 KB (hpub double buffer)
    int*      flags = (int*)(ws + 172097536);         // 4 KB barrier flags

    hipMemsetAsync(flags, 0, 4096, stream);
    // x fp32 -> f16
    convert_f32_f16<<<16384, 256, 0, stream>>>(x, x16, BATCH * SEQ * IS / 4);
    // weight transposes (fp32 [512][2048] -> f16 [2048][512])
    transpose_w<<<256, 256, 0, stream>>>(wih, wtih);
    transpose_w<<<256, 256, 0, stream>>>(whh, wthh);
    // input projection (writes scan-friendly xp layout)
    gemm_xproj<<<4096, 256, 0, stream>>>(x16, wtih, xp);
    // recurrent scan — REGULAR launch (32 blocks trivially co-resident on 256 CUs)
    lstm_scan<<<32, 256, 0, stream>>>(xp, wthh, hb, bias, h0, c0, out, flags);
}